// Round 3
// baseline (1281.019 us; speedup 1.0000x reference)
//
#include <hip/hip_runtime.h>
#include <hip/hip_bf16.h>
#include <math.h>

#define HIDDEN 768
#define NROWS 4096
#define QDIM 1024
#define VOCAB 30522
#define NPAD 30592   /* 239 * 128 */
#define NBX 239      /* NPAD/128 */
#define NBY 32       /* NROWS/128 */
#define NWG (NBX * NBY)  /* 7648, divisible by 8 */
#define NT (QDIM / 64)   /* 16 K-tiles */

typedef _Float16 half8 __attribute__((ext_vector_type(8)));
typedef float floatx4 __attribute__((ext_vector_type(4)));

// async global->LDS, 16B per lane. LDS dest is wave-uniform base + lane*16 (linear).
__device__ __forceinline__ void gload16(const _Float16* g, _Float16* l) {
  __builtin_amdgcn_global_load_lds(
      (const __attribute__((address_space(1))) void*)g,
      (__attribute__((address_space(3))) void*)l, 16, 0, 0);
}

// ---------------- proj_w (fp32 [K=1024][N=30522]) -> BT f16 [NPAD][1024] ----------------
__global__ __launch_bounds__(1024) void convert_transpose(
    const float* __restrict__ B, _Float16* __restrict__ BT) {
  __shared__ _Float16 tile[32][33];
  int n0 = blockIdx.x * 32;
  int k0 = blockIdx.y * 32;
  int tx = threadIdx.x, ty = threadIdx.y;
  int n = n0 + tx, k = k0 + ty;
  float v = (n < VOCAB) ? B[k * VOCAB + n] : 0.0f;
  tile[ty][tx] = (_Float16)v;
  __syncthreads();
  // write BT[n0+ty][k0+tx]  (coalesced in k)
  BT[(n0 + ty) * QDIM + (k0 + tx)] = tile[tx][ty];
}

// ---------------- Stage 1: h = gelu(hs @ W + b), fp32 64x64 tile ----------------
__global__ __launch_bounds__(256) void gemm1_gelu(
    const float* __restrict__ A, const float* __restrict__ W,
    const float* __restrict__ bias, float* __restrict__ H) {
  __shared__ float As[64][17];
  __shared__ float Bs[16][68];
  int t = threadIdx.x;
  int bm = blockIdx.y * 64, bn = blockIdx.x * 64;
  int tx = t & 15, ty = t >> 4;
  float acc[4][4] = {};
  for (int k0 = 0; k0 < HIDDEN; k0 += 16) {
    {
      int r = t >> 2, c = (t & 3) * 4;
      float4 v = *(const float4*)&A[(bm + r) * HIDDEN + k0 + c];
      As[r][c] = v.x; As[r][c + 1] = v.y; As[r][c + 2] = v.z; As[r][c + 3] = v.w;
    }
    {
      int kr = t >> 4, c = (t & 15) * 4;
      float4 v = *(const float4*)&W[(k0 + kr) * HIDDEN + bn + c];
      Bs[kr][c] = v.x; Bs[kr][c + 1] = v.y; Bs[kr][c + 2] = v.z; Bs[kr][c + 3] = v.w;
    }
    __syncthreads();
#pragma unroll
    for (int k = 0; k < 16; k++) {
      float a[4], b[4];
#pragma unroll
      for (int i = 0; i < 4; i++) a[i] = As[ty * 4 + i][k];
#pragma unroll
      for (int j = 0; j < 4; j++) b[j] = Bs[k][tx * 4 + j];
#pragma unroll
      for (int i = 0; i < 4; i++)
#pragma unroll
        for (int j = 0; j < 4; j++) acc[i][j] += a[i] * b[j];
    }
    __syncthreads();
  }
#pragma unroll
  for (int i = 0; i < 4; i++) {
    int m = bm + ty * 4 + i;
#pragma unroll
    for (int j = 0; j < 4; j++) {
      int n = bn + tx * 4 + j;
      float x = acc[i][j] + bias[n];
      float g = x * 0.5f * (1.0f + erff(x * 0.70710678118654752f));
      H[m * HIDDEN + n] = g;
    }
  }
}

// ---------------- block reduction helper (256 threads) ----------------
__device__ inline float block_sum256(float v, float* red) {
  int t = threadIdx.x;
#pragma unroll
  for (int o = 32; o > 0; o >>= 1) v += __shfl_down(v, o);
  __syncthreads();  // protect previous red use
  if ((t & 63) == 0) red[t >> 6] = v;
  __syncthreads();
  return red[0] + red[1] + red[2] + red[3];
}

// ---------------- Stage 2+3: LN -> ent matvec -> sigmoid -> quantum sim -> probs(f16) ----------------
__global__ __launch_bounds__(256) void row_quantum(
    const float* __restrict__ H, const float* __restrict__ ln_w,
    const float* __restrict__ ln_b, const float* __restrict__ ent_w,
    const float* __restrict__ ent_b, _Float16* __restrict__ probsA) {
  __shared__ float hn[HIDDEN];
  __shared__ float red[4];
  __shared__ float sr[QDIM];
  __shared__ float si[QDIM];
  __shared__ float ang[20];
  int t = threadIdx.x;
  int row = blockIdx.x;
  const float* hr = H + row * HIDDEN;

  float sum = 0.f;
  for (int i = t; i < HIDDEN; i += 256) {
    float v = hr[i];
    hn[i] = v;
    sum += v;
  }
  float u = block_sum256(sum, red) * (1.0f / HIDDEN);
  float vs = 0.f;
  for (int i = t; i < HIDDEN; i += 256) {
    float d = hn[i] - u;
    vs += d * d;
  }
  float var = block_sum256(vs, red) * (1.0f / HIDDEN);
  float inv = rsqrtf(var + 1e-12f);
  for (int i = t; i < HIDDEN; i += 256)
    hn[i] = ln_w[i] * ((hn[i] - u) * inv) + ln_b[i];
  __syncthreads();

  // ent matvec: 20 outputs, threads 0..19 each a full dot (hn broadcast from LDS)
  if (t < 20) {
    float acc = ent_b[t];
#pragma unroll 4
    for (int i = 0; i < HIDDEN; i++) acc += hn[i] * ent_w[i * 20 + t];
    float s = 1.0f / (1.0f + expf(-acc));
    ang[t] = 6.283185307179586f * s;
  }
  __syncthreads();

  // init |0...0>
  for (int i = t; i < QDIM; i += 256) {
    sr[i] = (i == 0) ? 1.0f : 0.0f;
    si[i] = 0.0f;
  }
  __syncthreads();

  for (int l = 0; l < 2; l++) {
    for (int q = 0; q < 10; q++) {
      float th = ang[l * 10 + q] * 0.5f;
      float c = cosf(th), s = sinf(th);
      int bp = 9 - q;
      int mask = 1 << bp;
#pragma unroll
      for (int p = 0; p < 2; p++) {
        int pi = t + p * 256;  // 0..511
        int i0 = ((pi >> bp) << (bp + 1)) | (pi & (mask - 1));
        int i1 = i0 | mask;
        float a0r = sr[i0], a0i = si[i0], a1r = sr[i1], a1i = si[i1];
        sr[i0] = c * a0r + s * a1i;
        si[i0] = c * a0i - s * a1r;
        sr[i1] = c * a1r + s * a0i;
        si[i1] = c * a1i - s * a0r;
      }
      __syncthreads();
    }
    // CNOT ring: composed permutation, new[i] = old[P0(P1(...P9(i)))]
    float tr[4], ti[4];
#pragma unroll
    for (int p = 0; p < 4; p++) {
      int i = t + p * 256;
      int j = i;
#pragma unroll
      for (int q = 9; q >= 0; q--) {
        int cb = 9 - q;              // control bit position
        int tb = 9 - ((q + 1) % 10); // target bit position
        j ^= ((j >> cb) & 1) << tb;
      }
      tr[p] = sr[j];
      ti[p] = si[j];
    }
    __syncthreads();
#pragma unroll
    for (int p = 0; p < 4; p++) {
      int i = t + p * 256;
      sr[i] = tr[p];
      si[i] = ti[p];
    }
    __syncthreads();
  }

  for (int i = t; i < QDIM; i += 256) {
    float pv = sr[i] * sr[i] + si[i] * si[i];
    probsA[row * QDIM + i] = (_Float16)pv;
  }
}

// ---------------- Stage 4: out = probs @ proj_w + b ----------------
// 128x128 tile, BK=64, global_load_lds width=16, DOUBLE-BUFFERED with counted
// vmcnt prefetch (T3-min + T4): issue next tile's loads BEFORE computing current,
// wait only vmcnt(8) (current tile's loads) + raw s_barrier — never drain to 0
// in the main loop. XOR slot-swizzle on source+read (both-sides, rule 21).
// T5: setprio(1) around MFMA cluster. XCD-aware bijective block swizzle.
__global__ __launch_bounds__(256) void gemm2_mfma(
    const _Float16* __restrict__ A,   // [4096][1024] f16
    const _Float16* __restrict__ BT,  // [NPAD][1024] f16 (B transposed)
    const float* __restrict__ bias,   // [VOCAB]
    float* __restrict__ C) {
  __shared__ _Float16 As[2][128][64];   // 2 x 16 KB
  __shared__ _Float16 Bs[2][128][64];   // 2 x 16 KB

  int t = threadIdx.x;
  int lane = t & 63, wave = t >> 6;
  int quad = lane >> 4, ln = lane & 15;
  int wm = (wave >> 1) * 64, wn = (wave & 1) * 64;

  // XCD-aware bijective swizzle: NWG=7648 divisible by 8. Column-major tile
  // order so each XCD's contiguous chunk reuses one BT panel from its L2.
  int wg = blockIdx.x;
  int swz = (wg & 7) * (NWG / 8) + (wg >> 3);
  int bn = (swz >> 5) * 128;   // bx = swz / 32
  int bm = (swz & 31) * 128;   // by = swz % 32

  // staging: thread t stages 16B -> LDS linear offset t*16 (+ i*4096) per buffer
  int srow = t >> 3;                 // row within 32-row group, 0..31
  int ps = t & 7;                    // physical 16B slot
  int lslot = ps ^ (srow & 7);       // logical slot held at phys slot
  const _Float16* gA = A  + (size_t)(bm + srow) * QDIM + lslot * 8;
  const _Float16* gB = BT + (size_t)(bn + srow) * QDIM + lslot * 8;

  // fragment-read swizzled offsets: row&7 == ln&7 for all fragments
  int r7 = ln & 7;
  int off0 = ((0 * 4 + quad) ^ r7) * 8;   // k-sub 0
  int off1 = ((1 * 4 + quad) ^ r7) * 8;   // k-sub 1

  floatx4 acc[4][4];
#pragma unroll
  for (int i = 0; i < 4; i++)
#pragma unroll
    for (int j = 0; j < 4; j++) acc[i][j] = (floatx4){0.f, 0.f, 0.f, 0.f};

  // stage tile kt into buffer b (8 global_load_lds, issue-only)
  auto STAGE = [&](int kt, int b) {
#pragma unroll
    for (int i = 0; i < 4; i++) {
      gload16(gA + (size_t)i * 32 * QDIM + kt * 64, &As[b][srow + i * 32][ps * 8]);
      gload16(gB + (size_t)i * 32 * QDIM + kt * 64, &Bs[b][srow + i * 32][ps * 8]);
    }
  };

  auto COMPUTE = [&](int b) {
    __builtin_amdgcn_s_setprio(1);
#pragma unroll
    for (int s = 0; s < 2; s++) {
      int off = s ? off1 : off0;
      half8 a[4], bb[4];
#pragma unroll
      for (int i = 0; i < 4; i++) a[i] = *(const half8*)&As[b][wm + i * 16 + ln][off];
#pragma unroll
      for (int j = 0; j < 4; j++) bb[j] = *(const half8*)&Bs[b][wn + j * 16 + ln][off];
#pragma unroll
      for (int i = 0; i < 4; i++)
#pragma unroll
        for (int j = 0; j < 4; j++)
          acc[i][j] = __builtin_amdgcn_mfma_f32_16x16x32_f16(a[i], bb[j], acc[i][j], 0, 0, 0);
    }
    __builtin_amdgcn_s_setprio(0);
  };

  // prologue: stage tile 0 into buf 0
  STAGE(0, 0);
  int cur = 0;
  for (int kt = 0; kt < NT - 1; ++kt) {
    STAGE(kt + 1, cur ^ 1);                       // prefetch next (8 more in flight)
    asm volatile("s_waitcnt vmcnt(8)" ::: "memory");  // wait current tile's 8 only
    __builtin_amdgcn_s_barrier();                 // all waves' current-tile data in LDS
    COMPUTE(cur);                                 // lgkmcnt waits force ds_reads done
    __builtin_amdgcn_s_barrier();                 // protect buf `cur` before overwrite
    cur ^= 1;
  }
  // final tile: drain everything
  asm volatile("s_waitcnt vmcnt(0)" ::: "memory");
  __builtin_amdgcn_s_barrier();
  COMPUTE(cur);

#pragma unroll
  for (int j = 0; j < 4; j++) {
    int n = bn + wn + j * 16 + ln;
    if (n >= VOCAB) continue;
    float bv = bias[n];
#pragma unroll
    for (int i = 0; i < 4; i++) {
#pragma unroll
      for (int r = 0; r < 4; r++) {
        int m = bm + wm + i * 16 + quad * 4 + r;
        C[(size_t)m * VOCAB + n] = acc[i][j][r] + bv;
      }
    }
  }
}

extern "C" void kernel_launch(void* const* d_in, const int* in_sizes, int n_in,
                              void* d_out, int out_size, void* d_ws, size_t ws_size,
                              hipStream_t stream) {
  const float* hs      = (const float*)d_in[0];
  const float* dense_w = (const float*)d_in[1];
  const float* dense_b = (const float*)d_in[2];
  const float* ln_w    = (const float*)d_in[3];
  const float* ln_b    = (const float*)d_in[4];
  const float* ent_w   = (const float*)d_in[5];
  const float* ent_b   = (const float*)d_in[6];
  const float* proj_w  = (const float*)d_in[7];
  const float* proj_b  = (const float*)d_in[8];
  float* out = (float*)d_out;

  char* ws = (char*)d_ws;
  float*     h      = (float*)ws;                       // 4096*768*4  = 12582912 B
  _Float16*  probsA = (_Float16*)(ws + 12582912);       // 4096*1024*2 =  8388608 B
  _Float16*  BT     = (_Float16*)(ws + 20971520);       // NPAD*1024*2 = 62652416 B

  hipLaunchKernelGGL(convert_transpose, dim3(NPAD / 32, QDIM / 32), dim3(32, 32), 0, stream,
                     proj_w, BT);
  hipLaunchKernelGGL(gemm1_gelu, dim3(HIDDEN / 64, NROWS / 64), dim3(256), 0, stream,
                     hs, dense_w, dense_b, h);
  hipLaunchKernelGGL(row_quantum, dim3(NROWS), dim3(256), 0, stream,
                     h, ln_w, ln_b, ent_w, ent_b, probsA);
  hipLaunchKernelGGL(gemm2_mfma, dim3(NWG), dim3(256), 0, stream,
                     probsA, BT, proj_b, out);
}

// Round 4
// 1143.221 us; speedup vs baseline: 1.1205x; 1.1205x over previous
//
#include <hip/hip_runtime.h>
#include <hip/hip_bf16.h>
#include <math.h>

#define HIDDEN 768
#define NROWS 4096
#define QDIM 1024
#define VOCAB 30522
#define NPAD 30592   /* 239 * 128 */
#define NBX 239      /* NPAD/128 */
#define NBY 32       /* NROWS/128 */
#define NWG (NBX * NBY)  /* 7648, divisible by 8 */
#define NT (QDIM / 64)   /* 16 K-tiles */

typedef _Float16 half8 __attribute__((ext_vector_type(8)));
typedef float floatx4 __attribute__((ext_vector_type(4)));
typedef float floatx2 __attribute__((ext_vector_type(2)));

// async global->LDS, 16B per lane. LDS dest is wave-uniform base + lane*16 (linear).
__device__ __forceinline__ void gload16(const _Float16* g, _Float16* l) {
  __builtin_amdgcn_global_load_lds(
      (const __attribute__((address_space(1))) void*)g,
      (__attribute__((address_space(3))) void*)l, 16, 0, 0);
}

// ---------------- proj_w (fp32 [K=1024][N=30522]) -> BT f16 [NPAD][1024] ----------------
__global__ __launch_bounds__(1024) void convert_transpose(
    const float* __restrict__ B, _Float16* __restrict__ BT) {
  __shared__ _Float16 tile[32][33];
  int n0 = blockIdx.x * 32;
  int k0 = blockIdx.y * 32;
  int tx = threadIdx.x, ty = threadIdx.y;
  int n = n0 + tx, k = k0 + ty;
  float v = (n < VOCAB) ? B[k * VOCAB + n] : 0.0f;
  tile[ty][tx] = (_Float16)v;
  __syncthreads();
  // write BT[n0+ty][k0+tx]  (coalesced in k)
  BT[(n0 + ty) * QDIM + (k0 + tx)] = tile[tx][ty];
}

// ---------------- Stage 1: h = gelu(hs @ W + b), fp32 64x64 tile ----------------
__global__ __launch_bounds__(256) void gemm1_gelu(
    const float* __restrict__ A, const float* __restrict__ W,
    const float* __restrict__ bias, float* __restrict__ H) {
  __shared__ float As[64][17];
  __shared__ float Bs[16][68];
  int t = threadIdx.x;
  int bm = blockIdx.y * 64, bn = blockIdx.x * 64;
  int tx = t & 15, ty = t >> 4;
  float acc[4][4] = {};
  for (int k0 = 0; k0 < HIDDEN; k0 += 16) {
    {
      int r = t >> 2, c = (t & 3) * 4;
      float4 v = *(const float4*)&A[(bm + r) * HIDDEN + k0 + c];
      As[r][c] = v.x; As[r][c + 1] = v.y; As[r][c + 2] = v.z; As[r][c + 3] = v.w;
    }
    {
      int kr = t >> 4, c = (t & 15) * 4;
      float4 v = *(const float4*)&W[(k0 + kr) * HIDDEN + bn + c];
      Bs[kr][c] = v.x; Bs[kr][c + 1] = v.y; Bs[kr][c + 2] = v.z; Bs[kr][c + 3] = v.w;
    }
    __syncthreads();
#pragma unroll
    for (int k = 0; k < 16; k++) {
      float a[4], b[4];
#pragma unroll
      for (int i = 0; i < 4; i++) a[i] = As[ty * 4 + i][k];
#pragma unroll
      for (int j = 0; j < 4; j++) b[j] = Bs[k][tx * 4 + j];
#pragma unroll
      for (int i = 0; i < 4; i++)
#pragma unroll
        for (int j = 0; j < 4; j++) acc[i][j] += a[i] * b[j];
    }
    __syncthreads();
  }
#pragma unroll
  for (int i = 0; i < 4; i++) {
    int m = bm + ty * 4 + i;
#pragma unroll
    for (int j = 0; j < 4; j++) {
      int n = bn + tx * 4 + j;
      float x = acc[i][j] + bias[n];
      float g = x * 0.5f * (1.0f + erff(x * 0.70710678118654752f));
      H[m * HIDDEN + n] = g;
    }
  }
}

// ---------------- block reduction helper (256 threads) ----------------
__device__ inline float block_sum256(float v, float* red) {
  int t = threadIdx.x;
#pragma unroll
  for (int o = 32; o > 0; o >>= 1) v += __shfl_down(v, o);
  __syncthreads();  // protect previous red use
  if ((t & 63) == 0) red[t >> 6] = v;
  __syncthreads();
  return red[0] + red[1] + red[2] + red[3];
}

// ---------------- Stage 2+3: LN -> ent matvec -> sigmoid -> quantum sim -> probs(f16) ----------------
__global__ __launch_bounds__(256) void row_quantum(
    const float* __restrict__ H, const float* __restrict__ ln_w,
    const float* __restrict__ ln_b, const float* __restrict__ ent_w,
    const float* __restrict__ ent_b, _Float16* __restrict__ probsA) {
  __shared__ float hn[HIDDEN];
  __shared__ float red[4];
  __shared__ float sr[QDIM];
  __shared__ float si[QDIM];
  __shared__ float ang[20];
  int t = threadIdx.x;
  int row = blockIdx.x;
  const float* hr = H + row * HIDDEN;

  float sum = 0.f;
  for (int i = t; i < HIDDEN; i += 256) {
    float v = hr[i];
    hn[i] = v;
    sum += v;
  }
  float u = block_sum256(sum, red) * (1.0f / HIDDEN);
  float vs = 0.f;
  for (int i = t; i < HIDDEN; i += 256) {
    float d = hn[i] - u;
    vs += d * d;
  }
  float var = block_sum256(vs, red) * (1.0f / HIDDEN);
  float inv = rsqrtf(var + 1e-12f);
  for (int i = t; i < HIDDEN; i += 256)
    hn[i] = ln_w[i] * ((hn[i] - u) * inv) + ln_b[i];
  __syncthreads();

  // ent matvec: wave w computes outputs o = w*5 + kk (4 waves x 5 outputs = 20),
  // 64 lanes strided over HIDDEN + shuffle reduce (wave-parallel, no serial section)
  {
    int w = t >> 6, lane = t & 63;
#pragma unroll
    for (int kk = 0; kk < 5; kk++) {
      int o = w * 5 + kk;
      float p = 0.f;
#pragma unroll
      for (int i = 0; i < HIDDEN / 64; i++)   // 12 iters
        p += hn[lane + i * 64] * ent_w[(lane + i * 64) * 20 + o];
#pragma unroll
      for (int off = 32; off > 0; off >>= 1) p += __shfl_down(p, off);
      if (lane == 0) {
        float acc = p + ent_b[o];
        float s = 1.0f / (1.0f + expf(-acc));
        ang[o] = 6.283185307179586f * s;
      }
    }
  }
  __syncthreads();

  // init |0...0>
  for (int i = t; i < QDIM; i += 256) {
    sr[i] = (i == 0) ? 1.0f : 0.0f;
    si[i] = 0.0f;
  }
  __syncthreads();

  for (int l = 0; l < 2; l++) {
    for (int q = 0; q < 10; q++) {
      float th = ang[l * 10 + q] * 0.5f;
      float c = cosf(th), s = sinf(th);
      int bp = 9 - q;
      int mask = 1 << bp;
#pragma unroll
      for (int p = 0; p < 2; p++) {
        int pi = t + p * 256;  // 0..511
        int i0 = ((pi >> bp) << (bp + 1)) | (pi & (mask - 1));
        int i1 = i0 | mask;
        float a0r = sr[i0], a0i = si[i0], a1r = sr[i1], a1i = si[i1];
        sr[i0] = c * a0r + s * a1i;
        si[i0] = c * a0i - s * a1r;
        sr[i1] = c * a1r + s * a0i;
        si[i1] = c * a1i - s * a0r;
      }
      __syncthreads();
    }
    // CNOT ring: composed permutation, new[i] = old[P0(P1(...P9(i)))]
    float tr[4], ti[4];
#pragma unroll
    for (int p = 0; p < 4; p++) {
      int i = t + p * 256;
      int j = i;
#pragma unroll
      for (int q = 9; q >= 0; q--) {
        int cb = 9 - q;              // control bit position
        int tb = 9 - ((q + 1) % 10); // target bit position
        j ^= ((j >> cb) & 1) << tb;
      }
      tr[p] = sr[j];
      ti[p] = si[j];
    }
    __syncthreads();
#pragma unroll
    for (int p = 0; p < 4; p++) {
      int i = t + p * 256;
      sr[i] = tr[p];
      si[i] = ti[p];
    }
    __syncthreads();
  }

  for (int i = t; i < QDIM; i += 256) {
    float pv = sr[i] * sr[i] + si[i] * si[i];
    probsA[row * QDIM + i] = (_Float16)pv;
  }
}

// ---------------- Stage 4: out = probs @ proj_w + b ----------------
// 128x128 tile, BK=64, global_load_lds w=16, double-buffered counted-vmcnt
// prefetch, XOR slot-swizzle (source+read). NEW: LDS-transpose epilogue +
// NON-TEMPORAL streaming C stores (keep A/BT resident in Infinity Cache —
// Round-3 counters showed 825 MB HBM fetch vs 70 MB unique input because the
// 500 MB C-write stream thrashes L3).
__global__ __launch_bounds__(256) void gemm2_mfma(
    const _Float16* __restrict__ A,   // [4096][1024] f16
    const _Float16* __restrict__ BT,  // [NPAD][1024] f16 (B transposed)
    const float* __restrict__ bias,   // [VOCAB]
    float* __restrict__ C) {
  __shared__ __align__(16) char smem_raw[65536];
  auto As = (_Float16 (*)[128][64])(smem_raw);           // [2][128][64], 32 KB
  auto Bs = (_Float16 (*)[128][64])(smem_raw + 32768);   // [2][128][64], 32 KB

  int t = threadIdx.x;
  int lane = t & 63, wave = t >> 6;
  int quad = lane >> 4, ln = lane & 15;
  int wm = (wave >> 1) * 64, wn = (wave & 1) * 64;

  // XCD-aware bijective swizzle: NWG=7648 divisible by 8. Column-major tile
  // order so each XCD's contiguous chunk reuses one BT panel from its L2.
  int wg = blockIdx.x;
  int swz = (wg & 7) * (NWG / 8) + (wg >> 3);
  int bn = (swz >> 5) * 128;   // bx = swz / 32
  int bm = (swz & 31) * 128;   // by = swz % 32

  // staging: thread t stages 16B -> LDS linear offset t*16 (+ i*4096) per buffer
  int srow = t >> 3;                 // row within 32-row group, 0..31
  int ps = t & 7;                    // physical 16B slot
  int lslot = ps ^ (srow & 7);       // logical slot held at phys slot
  const _Float16* gA = A  + (size_t)(bm + srow) * QDIM + lslot * 8;
  const _Float16* gB = BT + (size_t)(bn + srow) * QDIM + lslot * 8;

  // fragment-read swizzled offsets: row&7 == ln&7 for all fragments
  int r7 = ln & 7;
  int off0 = ((0 * 4 + quad) ^ r7) * 8;   // k-sub 0
  int off1 = ((1 * 4 + quad) ^ r7) * 8;   // k-sub 1

  floatx4 acc[4][4];
#pragma unroll
  for (int i = 0; i < 4; i++)
#pragma unroll
    for (int j = 0; j < 4; j++) acc[i][j] = (floatx4){0.f, 0.f, 0.f, 0.f};

  // stage tile kt into buffer b (8 global_load_lds, issue-only)
  auto STAGE = [&](int kt, int b) {
#pragma unroll
    for (int i = 0; i < 4; i++) {
      gload16(gA + (size_t)i * 32 * QDIM + kt * 64, &As[b][srow + i * 32][ps * 8]);
      gload16(gB + (size_t)i * 32 * QDIM + kt * 64, &Bs[b][srow + i * 32][ps * 8]);
    }
  };

  auto COMPUTE = [&](int b) {
    __builtin_amdgcn_s_setprio(1);
#pragma unroll
    for (int s = 0; s < 2; s++) {
      int off = s ? off1 : off0;
      half8 a[4], bb[4];
#pragma unroll
      for (int i = 0; i < 4; i++) a[i] = *(const half8*)&As[b][wm + i * 16 + ln][off];
#pragma unroll
      for (int j = 0; j < 4; j++) bb[j] = *(const half8*)&Bs[b][wn + j * 16 + ln][off];
#pragma unroll
      for (int i = 0; i < 4; i++)
#pragma unroll
        for (int j = 0; j < 4; j++)
          acc[i][j] = __builtin_amdgcn_mfma_f32_16x16x32_f16(a[i], bb[j], acc[i][j], 0, 0, 0);
    }
    __builtin_amdgcn_s_setprio(0);
  };

  // prologue: stage tile 0 into buf 0
  STAGE(0, 0);
  int cur = 0;
  for (int kt = 0; kt < NT - 1; ++kt) {
    STAGE(kt + 1, cur ^ 1);                           // prefetch next
    asm volatile("s_waitcnt vmcnt(8)" ::: "memory");  // wait current tile's 8 only
    __builtin_amdgcn_s_barrier();                     // current-tile data visible
    COMPUTE(cur);
    __builtin_amdgcn_s_barrier();                     // protect buf before overwrite
    cur ^= 1;
  }
  asm volatile("s_waitcnt vmcnt(0)" ::: "memory");
  __builtin_amdgcn_s_barrier();
  COMPUTE(cur);

  // ---- epilogue: transpose through LDS, stream out with NT stores ----
  __syncthreads();                       // all waves done with As/Bs ds_reads
  float* ctile = (float*)smem_raw;       // 128x128 f32 = 64 KB
#pragma unroll
  for (int j = 0; j < 4; j++)
#pragma unroll
    for (int i = 0; i < 4; i++)
#pragma unroll
      for (int r = 0; r < 4; r++)
        ctile[(wm + i * 16 + quad * 4 + r) * 128 + wn + j * 16 + ln] = acc[i][j][r];
  __syncthreads();

  if (bn + 128 <= VOCAB) {
    // full tile: 8192 float2 chunks; wave = 512 contiguous bytes per iter.
    // float2 (8B): C rows are only 8B-aligned (VOCAB*4 % 16 == 8).
#pragma unroll 4
    for (int idx = t; idx < 8192; idx += 256) {
      int row = idx >> 6;
      int c2 = (idx & 63) * 2;
      floatx2 v = *(const floatx2*)&ctile[row * 128 + c2];
      floatx2 bv = *(const floatx2*)&bias[bn + c2];
      v[0] += bv[0]; v[1] += bv[1];
      __builtin_nontemporal_store(
          v, (floatx2*)&C[(size_t)(bm + row) * VOCAB + bn + c2]);
    }
  } else {
    // edge tile (bn == 30464): scalar masked path, 32 of 7648 blocks
    for (int idx = t; idx < 8192; idx += 256) {
      int row = idx >> 6;
      int c2 = (idx & 63) * 2;
#pragma unroll
      for (int e = 0; e < 2; e++) {
        int n = bn + c2 + e;
        if (n < VOCAB)
          C[(size_t)(bm + row) * VOCAB + n] = ctile[row * 128 + c2 + e] + bias[n];
      }
    }
  }
}

extern "C" void kernel_launch(void* const* d_in, const int* in_sizes, int n_in,
                              void* d_out, int out_size, void* d_ws, size_t ws_size,
                              hipStream_t stream) {
  const float* hs      = (const float*)d_in[0];
  const float* dense_w = (const float*)d_in[1];
  const float* dense_b = (const float*)d_in[2];
  const float* ln_w    = (const float*)d_in[3];
  const float* ln_b    = (const float*)d_in[4];
  const float* ent_w   = (const float*)d_in[5];
  const float* ent_b   = (const float*)d_in[6];
  const float* proj_w  = (const float*)d_in[7];
  const float* proj_b  = (const float*)d_in[8];
  float* out = (float*)d_out;

  char* ws = (char*)d_ws;
  float*     h      = (float*)ws;                       // 4096*768*4  = 12582912 B
  _Float16*  probsA = (_Float16*)(ws + 12582912);       // 4096*1024*2 =  8388608 B
  _Float16*  BT     = (_Float16*)(ws + 20971520);       // NPAD*1024*2 = 62652416 B

  hipLaunchKernelGGL(convert_transpose, dim3(NPAD / 32, QDIM / 32), dim3(32, 32), 0, stream,
                     proj_w, BT);
  hipLaunchKernelGGL(gemm1_gelu, dim3(HIDDEN / 64, NROWS / 64), dim3(256), 0, stream,
                     hs, dense_w, dense_b, h);
  hipLaunchKernelGGL(row_quantum, dim3(NROWS), dim3(256), 0, stream,
                     h, ln_w, ln_b, ent_w, ent_b, probsA);
  hipLaunchKernelGGL(gemm2_mfma, dim3(NWG), dim3(256), 0, stream,
                     probsA, BT, proj_b, out);
}

// Round 5
// 1088.837 us; speedup vs baseline: 1.1765x; 1.0499x over previous
//
#include <hip/hip_runtime.h>
#include <hip/hip_bf16.h>
#include <math.h>

#define HIDDEN 768
#define NROWS 4096
#define QDIM 1024
#define VOCAB 30522
#define NPAD 30592   /* 239 * 128 */
#define NBX 239      /* NPAD/128 */
#define NBY 32       /* NROWS/128 */
#define NWG (NBX * NBY)  /* 7648, divisible by 8 */
#define NT (QDIM / 64)   /* 16 K-tiles */

typedef _Float16 half8 __attribute__((ext_vector_type(8)));
typedef _Float16 half4 __attribute__((ext_vector_type(4)));
typedef float floatx4 __attribute__((ext_vector_type(4)));
typedef float floatx2 __attribute__((ext_vector_type(2)));

// async global->LDS, 16B per lane. LDS dest is wave-uniform base + lane*16 (linear).
__device__ __forceinline__ void gload16(const void* g, void* l) {
  __builtin_amdgcn_global_load_lds(
      (const __attribute__((address_space(1))) void*)g,
      (__attribute__((address_space(3))) void*)l, 16, 0, 0);
}

// ---------------- proj_w (fp32 [K=1024][N=30522]) -> BT f16 [NPAD][1024] ----------------
__global__ __launch_bounds__(1024) void convert_transpose(
    const float* __restrict__ B, _Float16* __restrict__ BT) {
  __shared__ _Float16 tile[32][33];
  int n0 = blockIdx.x * 32;
  int k0 = blockIdx.y * 32;
  int tx = threadIdx.x, ty = threadIdx.y;
  int n = n0 + tx, k = k0 + ty;
  float v = (n < VOCAB) ? B[k * VOCAB + n] : 0.0f;
  tile[ty][tx] = (_Float16)v;
  __syncthreads();
  BT[(n0 + ty) * QDIM + (k0 + tx)] = tile[tx][ty];
}

// ---------------- split hs (f32) -> A_hi + A_lo (f16), elementwise ----------------
__global__ __launch_bounds__(256) void split_hs(
    const float* __restrict__ X, _Float16* __restrict__ Hi, _Float16* __restrict__ Lo) {
  int idx4 = blockIdx.x * 256 + threadIdx.x;      // one float4 per thread
  float4 v = *(const float4*)&X[idx4 * 4];
  half4 h, l;
  float x;
  x = v.x; h[0] = (_Float16)x; l[0] = (_Float16)(x - (float)h[0]);
  x = v.y; h[1] = (_Float16)x; l[1] = (_Float16)(x - (float)h[1]);
  x = v.z; h[2] = (_Float16)x; l[2] = (_Float16)(x - (float)h[2]);
  x = v.w; h[3] = (_Float16)x; l[3] = (_Float16)(x - (float)h[3]);
  *(half4*)&Hi[idx4 * 4] = h;
  *(half4*)&Lo[idx4 * 4] = l;
}

// ---------------- dense_w (f32 [K=768][N=768]) -> WT_hi/lo (f16 [N][K]) ----------------
__global__ __launch_bounds__(1024) void split_wT(
    const float* __restrict__ W, _Float16* __restrict__ Hi, _Float16* __restrict__ Lo) {
  __shared__ float tile[32][33];
  int n0 = blockIdx.x * 32;
  int k0 = blockIdx.y * 32;
  int tx = threadIdx.x, ty = threadIdx.y;
  tile[ty][tx] = W[(k0 + ty) * HIDDEN + n0 + tx];
  __syncthreads();
  float x = tile[tx][ty];                 // = W[k0+tx][n0+ty]
  _Float16 h = (_Float16)x;
  _Float16 l = (_Float16)(x - (float)h);
  Hi[(n0 + ty) * HIDDEN + k0 + tx] = h;   // coalesced in k
  Lo[(n0 + ty) * HIDDEN + k0 + tx] = l;
}

// ---------------- Stage 1: h = gelu(hs @ W + b) via split-f16 MFMA ----------------
// C = Ah@Bh + Ah@Bl + Al@Bh  (f32 accumulate) — ~22 mantissa bits, fp32-grade.
// 64x64 tile, BK=64, global_load_lds staging with the same XOR slot-swizzle as gemm2.
__global__ __launch_bounds__(256) void gemm1_mfma(
    const _Float16* __restrict__ Ah, const _Float16* __restrict__ Al,  // [4096][768]
    const _Float16* __restrict__ Bh, const _Float16* __restrict__ Bl,  // [768][768] (BT layout [n][k])
    const float* __restrict__ bias, float* __restrict__ H) {
  __shared__ _Float16 sAh[64][64], sAl[64][64], sBh[64][64], sBl[64][64];  // 4 x 8 KB
  int t = threadIdx.x;
  int lane = t & 63, wave = t >> 6;
  int quad = lane >> 4, ln = lane & 15;
  int wm = (wave >> 1) * 32, wn = (wave & 1) * 32;
  int bm = blockIdx.y * 64, bn = blockIdx.x * 64;

  int srow = t >> 3;                 // 0..31
  int ps = t & 7;                    // physical 16B slot
  int lslot = ps ^ (srow & 7);       // logical slot at phys slot
  const _Float16* gAh = Ah + (size_t)(bm + srow) * HIDDEN + lslot * 8;
  const _Float16* gAl = Al + (size_t)(bm + srow) * HIDDEN + lslot * 8;
  const _Float16* gBh = Bh + (size_t)(bn + srow) * HIDDEN + lslot * 8;
  const _Float16* gBl = Bl + (size_t)(bn + srow) * HIDDEN + lslot * 8;

  int r7 = ln & 7;
  int off0 = ((0 * 4 + quad) ^ r7) * 8;
  int off1 = ((1 * 4 + quad) ^ r7) * 8;

  floatx4 acc[2][2];
#pragma unroll
  for (int i = 0; i < 2; i++)
#pragma unroll
    for (int j = 0; j < 2; j++) acc[i][j] = (floatx4){0.f, 0.f, 0.f, 0.f};

  for (int k0 = 0; k0 < HIDDEN; k0 += 64) {
    if (k0) __syncthreads();           // protect LDS before restaging
#pragma unroll
    for (int i = 0; i < 2; i++) {
      int ro = i * 32;
      gload16(gAh + (size_t)ro * HIDDEN + k0, &sAh[srow + ro][ps * 8]);
      gload16(gAl + (size_t)ro * HIDDEN + k0, &sAl[srow + ro][ps * 8]);
      gload16(gBh + (size_t)ro * HIDDEN + k0, &sBh[srow + ro][ps * 8]);
      gload16(gBl + (size_t)ro * HIDDEN + k0, &sBl[srow + ro][ps * 8]);
    }
    __syncthreads();                   // vmcnt drained before barrier
#pragma unroll
    for (int s = 0; s < 2; s++) {
      int off = s ? off1 : off0;
      half8 ah[2], al[2], bh[2], bl[2];
#pragma unroll
      for (int i = 0; i < 2; i++) {
        ah[i] = *(const half8*)&sAh[wm + i * 16 + ln][off];
        al[i] = *(const half8*)&sAl[wm + i * 16 + ln][off];
      }
#pragma unroll
      for (int j = 0; j < 2; j++) {
        bh[j] = *(const half8*)&sBh[wn + j * 16 + ln][off];
        bl[j] = *(const half8*)&sBl[wn + j * 16 + ln][off];
      }
#pragma unroll
      for (int i = 0; i < 2; i++)
#pragma unroll
        for (int j = 0; j < 2; j++) {
          acc[i][j] = __builtin_amdgcn_mfma_f32_16x16x32_f16(ah[i], bh[j], acc[i][j], 0, 0, 0);
          acc[i][j] = __builtin_amdgcn_mfma_f32_16x16x32_f16(ah[i], bl[j], acc[i][j], 0, 0, 0);
          acc[i][j] = __builtin_amdgcn_mfma_f32_16x16x32_f16(al[i], bh[j], acc[i][j], 0, 0, 0);
        }
    }
  }

#pragma unroll
  for (int j = 0; j < 2; j++) {
    int n = bn + wn + j * 16 + ln;
    float bv = bias[n];
#pragma unroll
    for (int i = 0; i < 2; i++)
#pragma unroll
      for (int r = 0; r < 4; r++) {
        int m = bm + wm + i * 16 + quad * 4 + r;
        float x = acc[i][j][r] + bv;
        float g = x * 0.5f * (1.0f + erff(x * 0.70710678118654752f));
        H[(size_t)m * HIDDEN + n] = g;
      }
  }
}

// ---------------- block reduction helper (256 threads) ----------------
__device__ inline float block_sum256(float v, float* red) {
  int t = threadIdx.x;
#pragma unroll
  for (int o = 32; o > 0; o >>= 1) v += __shfl_down(v, o);
  __syncthreads();
  if ((t & 63) == 0) red[t >> 6] = v;
  __syncthreads();
  return red[0] + red[1] + red[2] + red[3];
}

// ---------------- Stage 2+3: LN -> ent matvec -> sigmoid -> quantum sim -> probs(f16) ----------------
__global__ __launch_bounds__(256) void row_quantum(
    const float* __restrict__ H, const float* __restrict__ ln_w,
    const float* __restrict__ ln_b, const float* __restrict__ ent_w,
    const float* __restrict__ ent_b, _Float16* __restrict__ probsA) {
  __shared__ float hn[HIDDEN];
  __shared__ float red[4];
  __shared__ float sr[QDIM];
  __shared__ float si[QDIM];
  __shared__ float ang[20];
  int t = threadIdx.x;
  int row = blockIdx.x;
  const float* hr = H + row * HIDDEN;

  float sum = 0.f;
  for (int i = t; i < HIDDEN; i += 256) {
    float v = hr[i];
    hn[i] = v;
    sum += v;
  }
  float u = block_sum256(sum, red) * (1.0f / HIDDEN);
  float vs = 0.f;
  for (int i = t; i < HIDDEN; i += 256) {
    float d = hn[i] - u;
    vs += d * d;
  }
  float var = block_sum256(vs, red) * (1.0f / HIDDEN);
  float inv = rsqrtf(var + 1e-12f);
  for (int i = t; i < HIDDEN; i += 256)
    hn[i] = ln_w[i] * ((hn[i] - u) * inv) + ln_b[i];
  __syncthreads();

  // ent matvec: wave w computes outputs o = w*5 + kk; shuffle reduce, no serial section
  {
    int w = t >> 6, lane = t & 63;
#pragma unroll
    for (int kk = 0; kk < 5; kk++) {
      int o = w * 5 + kk;
      float p = 0.f;
#pragma unroll
      for (int i = 0; i < HIDDEN / 64; i++)
        p += hn[lane + i * 64] * ent_w[(lane + i * 64) * 20 + o];
#pragma unroll
      for (int off = 32; off > 0; off >>= 1) p += __shfl_down(p, off);
      if (lane == 0) {
        float acc = p + ent_b[o];
        float s = 1.0f / (1.0f + expf(-acc));
        ang[o] = 6.283185307179586f * s;
      }
    }
  }
  __syncthreads();

  for (int i = t; i < QDIM; i += 256) {
    sr[i] = (i == 0) ? 1.0f : 0.0f;
    si[i] = 0.0f;
  }
  __syncthreads();

  for (int l = 0; l < 2; l++) {
    for (int q = 0; q < 10; q++) {
      float th = ang[l * 10 + q] * 0.5f;
      float c = cosf(th), s = sinf(th);
      int bp = 9 - q;
      int mask = 1 << bp;
#pragma unroll
      for (int p = 0; p < 2; p++) {
        int pi = t + p * 256;
        int i0 = ((pi >> bp) << (bp + 1)) | (pi & (mask - 1));
        int i1 = i0 | mask;
        float a0r = sr[i0], a0i = si[i0], a1r = sr[i1], a1i = si[i1];
        sr[i0] = c * a0r + s * a1i;
        si[i0] = c * a0i - s * a1r;
        sr[i1] = c * a1r + s * a0i;
        si[i1] = c * a1i - s * a0r;
      }
      __syncthreads();
    }
    float tr[4], ti[4];
#pragma unroll
    for (int p = 0; p < 4; p++) {
      int i = t + p * 256;
      int j = i;
#pragma unroll
      for (int q = 9; q >= 0; q--) {
        int cb = 9 - q;
        int tb = 9 - ((q + 1) % 10);
        j ^= ((j >> cb) & 1) << tb;
      }
      tr[p] = sr[j];
      ti[p] = si[j];
    }
    __syncthreads();
#pragma unroll
    for (int p = 0; p < 4; p++) {
      int i = t + p * 256;
      sr[i] = tr[p];
      si[i] = ti[p];
    }
    __syncthreads();
  }

  for (int i = t; i < QDIM; i += 256) {
    float pv = sr[i] * sr[i] + si[i] * si[i];
    probsA[row * QDIM + i] = (_Float16)pv;
  }
}

// ---------------- Stage 4: out = probs @ proj_w + b ----------------
// 128x128 tile, BK=64, global_load_lds, dbuf counted-vmcnt prefetch, XOR swizzle,
// LDS-transpose epilogue (now bank-swizzled) + NT streaming C stores.
__global__ __launch_bounds__(256) void gemm2_mfma(
    const _Float16* __restrict__ A,   // [4096][1024] f16
    const _Float16* __restrict__ BT,  // [NPAD][1024] f16
    const float* __restrict__ bias,   // [VOCAB]
    float* __restrict__ C) {
  __shared__ __align__(16) char smem_raw[65536];
  auto As = (_Float16 (*)[128][64])(smem_raw);           // [2][128][64], 32 KB
  auto Bs = (_Float16 (*)[128][64])(smem_raw + 32768);   // [2][128][64], 32 KB

  int t = threadIdx.x;
  int lane = t & 63, wave = t >> 6;
  int quad = lane >> 4, ln = lane & 15;
  int wm = (wave >> 1) * 64, wn = (wave & 1) * 64;

  int wg = blockIdx.x;
  int swz = (wg & 7) * (NWG / 8) + (wg >> 3);
  int bn = (swz >> 5) * 128;
  int bm = (swz & 31) * 128;

  int srow = t >> 3;
  int ps = t & 7;
  int lslot = ps ^ (srow & 7);
  const _Float16* gA = A  + (size_t)(bm + srow) * QDIM + lslot * 8;
  const _Float16* gB = BT + (size_t)(bn + srow) * QDIM + lslot * 8;

  int r7 = ln & 7;
  int off0 = ((0 * 4 + quad) ^ r7) * 8;
  int off1 = ((1 * 4 + quad) ^ r7) * 8;

  floatx4 acc[4][4];
#pragma unroll
  for (int i = 0; i < 4; i++)
#pragma unroll
    for (int j = 0; j < 4; j++) acc[i][j] = (floatx4){0.f, 0.f, 0.f, 0.f};

  auto STAGE = [&](int kt, int b) {
#pragma unroll
    for (int i = 0; i < 4; i++) {
      gload16(gA + (size_t)i * 32 * QDIM + kt * 64, &As[b][srow + i * 32][ps * 8]);
      gload16(gB + (size_t)i * 32 * QDIM + kt * 64, &Bs[b][srow + i * 32][ps * 8]);
    }
  };

  auto COMPUTE = [&](int b) {
    __builtin_amdgcn_s_setprio(1);
#pragma unroll
    for (int s = 0; s < 2; s++) {
      int off = s ? off1 : off0;
      half8 a[4], bb[4];
#pragma unroll
      for (int i = 0; i < 4; i++) a[i] = *(const half8*)&As[b][wm + i * 16 + ln][off];
#pragma unroll
      for (int j = 0; j < 4; j++) bb[j] = *(const half8*)&Bs[b][wn + j * 16 + ln][off];
#pragma unroll
      for (int i = 0; i < 4; i++)
#pragma unroll
        for (int j = 0; j < 4; j++)
          acc[i][j] = __builtin_amdgcn_mfma_f32_16x16x32_f16(a[i], bb[j], acc[i][j], 0, 0, 0);
    }
    __builtin_amdgcn_s_setprio(0);
  };

  STAGE(0, 0);
  int cur = 0;
  for (int kt = 0; kt < NT - 1; ++kt) {
    STAGE(kt + 1, cur ^ 1);
    asm volatile("s_waitcnt vmcnt(8)" ::: "memory");
    __builtin_amdgcn_s_barrier();
    COMPUTE(cur);
    __builtin_amdgcn_s_barrier();
    cur ^= 1;
  }
  asm volatile("s_waitcnt vmcnt(0)" ::: "memory");
  __builtin_amdgcn_s_barrier();
  COMPUTE(cur);

  // ---- epilogue: transpose through LDS (bank-swizzled), stream out NT ----
  __syncthreads();
  float* ctile = (float*)smem_raw;       // 128x128 f32, col ^= ((row>>2)&3)<<4
#pragma unroll
  for (int j = 0; j < 4; j++)
#pragma unroll
    for (int i = 0; i < 4; i++)
#pragma unroll
      for (int r = 0; r < 4; r++) {
        int row = wm + i * 16 + quad * 4 + r;
        int col = (wn + j * 16 + ln) ^ (((row >> 2) & 3) << 4);
        ctile[row * 128 + col] = acc[i][j][r];
      }
  __syncthreads();

  if (bn + 128 <= VOCAB) {
#pragma unroll 4
    for (int idx = t; idx < 8192; idx += 256) {
      int row = idx >> 6;
      int c2 = (idx & 63) * 2;
      int pc = c2 ^ (((row >> 2) & 3) << 4);
      floatx2 v = *(const floatx2*)&ctile[row * 128 + pc];
      floatx2 bv = *(const floatx2*)&bias[bn + c2];
      v[0] += bv[0]; v[1] += bv[1];
      __builtin_nontemporal_store(
          v, (floatx2*)&C[(size_t)(bm + row) * VOCAB + bn + c2]);
    }
  } else {
    for (int idx = t; idx < 8192; idx += 256) {
      int row = idx >> 6;
      int c2 = (idx & 63) * 2;
      int pc = c2 ^ (((row >> 2) & 3) << 4);
#pragma unroll
      for (int e = 0; e < 2; e++) {
        int n = bn + c2 + e;
        if (n < VOCAB)
          C[(size_t)(bm + row) * VOCAB + n] = ctile[row * 128 + pc + e] + bias[n];
      }
    }
  }
}

extern "C" void kernel_launch(void* const* d_in, const int* in_sizes, int n_in,
                              void* d_out, int out_size, void* d_ws, size_t ws_size,
                              hipStream_t stream) {
  const float* hs      = (const float*)d_in[0];
  const float* dense_w = (const float*)d_in[1];
  const float* dense_b = (const float*)d_in[2];
  const float* ln_w    = (const float*)d_in[3];
  const float* ln_b    = (const float*)d_in[4];
  const float* ent_w   = (const float*)d_in[5];
  const float* ent_b   = (const float*)d_in[6];
  const float* proj_w  = (const float*)d_in[7];
  const float* proj_b  = (const float*)d_in[8];
  float* out = (float*)d_out;

  char* ws = (char*)d_ws;
  float*     h      = (float*)ws;                       // 0        : 12582912 B
  _Float16*  probsA = (_Float16*)(ws + 12582912);       // 12582912 :  8388608 B
  _Float16*  BT     = (_Float16*)(ws + 20971520);       // 20971520 : 62652416 B
  // split buffers ALIAS the BT region — consumed by gemm1 BEFORE convert_transpose
  // overwrites it (stream-serialized):
  _Float16*  Ahi = (_Float16*)(ws + 20971520);          // 6291456 B
  _Float16*  Alo = (_Float16*)(ws + 27262976);          // 6291456 B
  _Float16*  WThi = (_Float16*)(ws + 33554432);         // 1179648 B
  _Float16*  WTlo = (_Float16*)(ws + 34734080);         // 1179648 B

  hipLaunchKernelGGL(split_hs, dim3(NROWS * HIDDEN / 1024), dim3(256), 0, stream,
                     hs, Ahi, Alo);
  hipLaunchKernelGGL(split_wT, dim3(HIDDEN / 32, HIDDEN / 32), dim3(32, 32), 0, stream,
                     dense_w, WThi, WTlo);
  hipLaunchKernelGGL(gemm1_mfma, dim3(HIDDEN / 64, NROWS / 64), dim3(256), 0, stream,
                     Ahi, Alo, WThi, WTlo, dense_b, h);
  hipLaunchKernelGGL(row_quantum, dim3(NROWS), dim3(256), 0, stream,
                     h, ln_w, ln_b, ent_w, ent_b, probsA);
  hipLaunchKernelGGL(convert_transpose, dim3(NPAD / 32, QDIM / 32), dim3(32, 32), 0, stream,
                     proj_w, BT);
  hipLaunchKernelGGL(gemm2_mfma, dim3(NWG), dim3(256), 0, stream,
                     probsA, BT, proj_b, out);
}